// Round 10
// baseline (76.689 us; speedup 1.0000x reference)
//
#include <hip/hip_runtime.h>
#include <hip/hip_bf16.h>

#define KTOP 1000
#define NB 1024
#define CAP 2048
#define PCAP 1024
#define HBLK 32            // hist blocks per image
#define REL1 0.1f
#define REL2 0.05f

typedef unsigned long long u64;
typedef unsigned int u32;

__device__ __forceinline__ const float* pick_scores(const void* A, const void* B, int flag) {
    return flag ? (const float*)B : (const float*)A;   // flag=1 -> A is classes
}
__device__ __forceinline__ const int* pick_classes(const void* A, const void* B, int flag) {
    return flag ? (const int*)A : (const int*)B;
}

// flag=1 iff A looks like int class labels (all bit patterns < 256 over 256 probes).
__device__ __forceinline__ int block_flag(const void* pA, int tid, int* ldsf) {
    if (tid == 0) *ldsf = 0;
    __syncthreads();
    if (tid < 256) {
        u32 v = ((const u32*)pA)[tid];
        u64 big = __ballot(v >= 256u);
        if ((tid & 63) == 0 && big) atomicOr(ldsf, 1);
    }
    __syncthreads();
    return *ldsf ? 0 : 1;
}

__device__ __forceinline__ int bucket_of(float v) {
    int bu = (int)(v * (float)NB);           // *1024 exact (pow2) -> monotone
    return bu < 0 ? 0 : (bu > NB - 1 ? NB - 1 : bu);
}

// ---- kernel 1: per-block partial histograms, plain stores (no pre-zero needed) ----
__global__ __launch_bounds__(256) void hist_kernel(const void* __restrict__ pA,
                                                   const void* __restrict__ pB, int N,
                                                   int* __restrict__ phist) {  // [B][HBLK][NB]
    __shared__ int h[NB];
    __shared__ int ldsf;
    int b = blockIdx.y, blk = blockIdx.x;
    int t = threadIdx.x;
    int flag = block_flag(pA, t, &ldsf);
    for (int i = t; i < NB; i += 256) h[i] = 0;
    __syncthreads();
    const float* s = pick_scores(pA, pB, flag) + (size_t)b * N;
    const float4* s4 = (const float4*)s;
    int N4 = N >> 2;
    for (int i = blk * 256 + t; i < N4; i += gridDim.x * 256) {
        float4 v = s4[i];
        atomicAdd(&h[bucket_of(v.x)], 1);
        atomicAdd(&h[bucket_of(v.y)], 1);
        atomicAdd(&h[bucket_of(v.z)], 1);
        atomicAdd(&h[bucket_of(v.w)], 1);
    }
    for (int i = N4 * 4 + blk * 256 + t; i < N; i += gridDim.x * 256)
        atomicAdd(&h[bucket_of(s[i])], 1);
    __syncthreads();
    int4* dst = (int4*)(phist + ((size_t)b * HBLK + blk) * NB);
    dst[t] = make_int4(h[t * 4], h[t * 4 + 1], h[t * 4 + 2], h[t * 4 + 3]);
}

// ---- kernel 2: everything else, fused per image (1 block of 1024 per image) ----
__global__ __launch_bounds__(1024) void meganms_kernel(const void* __restrict__ pA,
                                                       const void* __restrict__ pB,
                                                       const float4* __restrict__ boxes, int N,
                                                       const int* __restrict__ phist,
                                                       float* __restrict__ out, int B) {
    __shared__ int hh[NB];          //  4096
    __shared__ int csum[256];       //  1024
    __shared__ u64 uni[CAP];        // 16384: key[] -> later myPos/pairs/sorted (disjoint lifetimes)
    __shared__ float4 sbox[KTOP];   // 16000
    __shared__ float sarea[KTOP];   //  4000
    __shared__ float sscore[KTOP];  //  4000
    __shared__ int scls[KTOP];      //  4000
    __shared__ short items[KTOP];   //  2000
    __shared__ int clsCnt[128];
    __shared__ int clsStart[128];
    __shared__ u64 keepw[16];
    __shared__ int firstIdx[128];
    __shared__ int wtot[16];
    __shared__ int ldsf, scut, mcnt, npair;

    u64* key   = uni;                      // phase A only
    int* myPos = (int*)uni;                // class-bucket phase only
    u32* pairs = (u32*)uni;                // pair phase (myPos dead)
    u32* sorted = ((u32*)uni) + PCAP;      // distinct from pairs

    int b = blockIdx.x;
    int tid = threadIdx.x;
    int lane = tid & 63;
    int wid = tid >> 6;

    int flag = block_flag(pA, tid, &ldsf);
    if (tid < 128) { clsCnt[tid] = 0; firstIdx[tid] = 0x7fffffff; }
    if (tid == 0) { mcnt = 0; npair = 0; }

    // ---- sum partial histograms (coalesced; one bucket per thread) ----
    {
        const int* src = phist + (size_t)b * HBLK * NB;
        int acc = 0;
#pragma unroll
        for (int blk = 0; blk < HBLK; ++blk) acc += src[blk * NB + tid];
        hh[tid] = acc;
    }
    __syncthreads();
    if (tid < 256) {
        int base = NB - 1 - tid * (NB / 256);
        int acc2 = 0;
#pragma unroll
        for (int k = 0; k < NB / 256; ++k) acc2 += hh[base - k];
        csum[tid] = acc2;
    }
    __syncthreads();
    if (tid == 0) {            // cutoff: bucket of the KTOP-th largest score (verbatim logic)
        int cum = 0, cut = 0;
        for (int u = 0; u < 256; ++u) {
            if (cum + csum[u] >= KTOP) {
                for (int k = 0; k < NB / 256; ++k) {
                    cum += hh[NB - 1 - u * (NB / 256) - k];
                    if (cum >= KTOP) { cut = NB - 1 - u * (NB / 256) - k; break; }
                }
                break;
            }
            cum += csum[u];
        }
        scut = cut;
    }
    __syncthreads();
    int cut = scut;

    // ---- scan scores, collect composite keys into LDS (order-free; ranked later) ----
    {
        const float* s = pick_scores(pA, pB, flag) + (size_t)b * N;
        const float4* s4 = (const float4*)s;
        int N4 = N >> 2;
        for (int i = tid; i < N4; i += 1024) {
            float4 v = s4[i];
            float vv[4] = {v.x, v.y, v.z, v.w};
#pragma unroll
            for (int k = 0; k < 4; ++k) {
                if (bucket_of(vv[k]) >= cut) {
                    int p = atomicAdd(&mcnt, 1);
                    if (p < CAP)
                        key[p] = ((u64)__float_as_uint(vv[k]) << 32) | (u32)(~(u32)(i * 4 + k));
                }
            }
        }
        for (int i = N4 * 4 + tid; i < N; i += 1024) {
            float v = s[i];
            if (bucket_of(v) >= cut) {
                int p = atomicAdd(&mcnt, 1);
                if (p < CAP)
                    key[p] = ((u64)__float_as_uint(v) << 32) | (u32)(~(u32)i);
            }
        }
    }
    __syncthreads();
    int M = mcnt; if (M > CAP) M = CAP;

    // ---- rank-by-count (exact top_k order: score desc, ties -> lower idx) + gather ----
    {
        int c0 = tid, c1 = tid + 1024;
        u64 kc0 = (c0 < M) ? key[c0] : 0;
        u64 kc1 = (c1 < M) ? key[c1] : 0;
        int r0 = 0, r1 = 0;
        for (int j = 0; j < M; ++j) {
            u64 kj = key[j];               // LDS broadcast
            r0 += (kj > kc0);
            r1 += (kj > kc1);
        }
        const int* classes = pick_classes(pA, pB, flag);
        if (c0 < M && r0 < KTOP) {
            int idx = (int)(~(u32)kc0);
            sscore[r0] = __uint_as_float((u32)(kc0 >> 32));
            scls[r0] = classes[(size_t)b * N + idx];
            sbox[r0] = boxes[(size_t)b * N + idx];
        }
        if (c1 < M && r1 < KTOP) {
            int idx = (int)(~(u32)kc1);
            sscore[r1] = __uint_as_float((u32)(kc1 >> 32));
            scls[r1] = classes[(size_t)b * N + idx];
            sbox[r1] = boxes[(size_t)b * N + idx];
        }
    }
    __syncthreads();   // key[] dead beyond this point (uni reused)

    // ---- class bucketing ----
    if (tid < KTOP) {
        float4 bx = sbox[tid];
        sarea[tid] = (bx.z - bx.x) * (bx.w - bx.y);
        myPos[tid] = atomicAdd(&clsCnt[scls[tid] & 127], 1);
    }
    __syncthreads();
    if (tid == 0) {
        int acc = 0;
        for (int c = 0; c < 128; ++c) { clsStart[c] = acc; acc += clsCnt[c]; }
    }
    __syncthreads();
    if (tid < KTOP) items[clsStart[scls[tid] & 127] + myPos[tid]] = (short)tid;
    __syncthreads();   // myPos dead beyond this point

    // ---- pair finding within class buckets (avg ~12.5 entries) ----
    if (tid < KTOP) {
        int i = tid;
        float4 bi = sbox[i];
        float ai = sarea[i];
        int ci = scls[i];
        int cb = ci & 127, s = clsStart[cb], n = clsCnt[cb];
        for (int q = 0; q < n; ++q) {
            int j = items[s + q];
            if (j <= i || scls[j] != ci) continue;
            float4 bj = sbox[j];
            float xx1 = fmaxf(bi.x, bj.x);
            float yy1 = fmaxf(bi.y, bj.y);
            float xx2 = fminf(bi.z, bj.z);
            float yy2 = fminf(bi.w, bj.w);
            float ww = fmaxf(xx2 - xx1, 0.f);
            float hh2 = fmaxf(yy2 - yy1, 0.f);
            float inter = ww * hh2;
            float iou = inter / (ai + sarea[j] - inter);   // exact reference op order
            if (iou > 0.5f) {
                int p = atomicAdd(&npair, 1);
                if (p < PCAP) pairs[p] = ((u32)i << 10) | (u32)j;
            }
        }
    }
    __syncthreads();

    int P = npair; if (P > PCAP) P = PCAP;
    if (tid < P) {                      // rank-sort ascending; keys unique
        u32 k = pairs[tid];
        int r = 0;
        for (int q = 0; q < P; ++q) r += (pairs[q] < k);
        sorted[r] = k;
    }
    __syncthreads();

    // ---- greedy walk over sorted pairs; wave 0, lane l<16 owns sup word l ----
    if (wid == 0) {
        u64 sup = 0;
        for (int p = 0; p < P; ++p) {
            u32 k = sorted[p];
            int i = k >> 10;
            u64 supw = __shfl(sup, i >> 6);
            if (((supw >> (i & 63)) & 1ull) == 0ull) {   // i kept -> suppress j
                int j = (int)(k & 1023u);
                if (lane == (j >> 6)) sup |= 1ull << (j & 63);
            }
        }
        if (lane < 16) keepw[lane] = ~sup;
    }
    __syncthreads();

    float s0 = sscore[0];   // index 0 never suppressed; scores descending

    for (int i = tid; i < KTOP; i += 1024) {
        bool kp = (keepw[i >> 6] >> (i & 63)) & 1ull;
        if (kp && sscore[i] >= REL1 * s0) atomicMin(&firstIdx[scls[i] & 127], i);
    }
    __syncthreads();

    bool fin = false;
    if (tid < KTOP) {
        bool kp = (keepw[tid >> 6] >> (tid & 63)) & 1ull;
        bool v3 = kp && (sscore[tid] >= REL1 * s0);
        if (v3) {
            int f = firstIdx[scls[tid] & 127];
            bool del = (f < tid) && (sscore[tid] < REL2 * sscore[f]);
            fin = !del;
        }
    }
    u64 m = __ballot(fin);
    if (lane == 0) wtot[wid] = __popcll(m);
    __syncthreads();
    int prefix = 0, V = 0;
    for (int k = 0; k < 16; ++k) { int c = wtot[k]; if (k < wid) prefix += c; V += c; }
    int rank = prefix + __popcll(m & ((1ull << lane) - 1ull));

    float* ob = out;                          // boxes  [B,100,4]
    float* oc = out + (size_t)B * 400;        // classes[B,100] (as float)
    float* os = out + (size_t)B * 500;        // scores [B,100]
    if (fin && rank < 100) {
        int o = b * 100 + rank;
        float4 bx = sbox[tid];
        ob[o * 4 + 0] = bx.x;
        ob[o * 4 + 1] = bx.y;
        ob[o * 4 + 2] = bx.z;
        ob[o * 4 + 3] = bx.w;
        oc[o] = (float)scls[tid];
        os[o] = sscore[tid];
    }
    int Vc = V < 100 ? V : 100;
    if (tid >= Vc && tid < 100) {
        int o = b * 100 + tid;
        ob[o * 4 + 0] = 0.f;
        ob[o * 4 + 1] = 0.f;
        ob[o * 4 + 2] = 0.f;
        ob[o * 4 + 3] = 0.f;
        oc[o] = -1.f;
        os[o] = 0.f;
    }
}

extern "C" void kernel_launch(void* const* d_in, const int* in_sizes, int n_in,
                              void* d_out, int out_size, void* d_ws, size_t ws_size,
                              hipStream_t stream) {
    (void)n_in; (void)ws_size;
    float* out = (float*)d_out;
    int B = out_size / 600;          // 100*(4+1+1) per image

    // identify boxes input purely from sizes (4N vs N); robust to any permutation
    int ib = 0;
    for (int i = 1; i < 3; ++i) if (in_sizes[i] > in_sizes[ib]) ib = i;
    int o1 = -1, o2 = -1;
    for (int i = 0; i < 3; ++i) if (i != ib) { if (o1 < 0) o1 = i; else o2 = i; }
    int N = in_sizes[o1] / B;
    const float4* boxes = (const float4*)d_in[ib];
    const void* pA = d_in[o1];
    const void* pB = d_in[o2];

    int* phist = (int*)d_ws;         // [B][HBLK][NB]; fully overwritten each call

    hist_kernel<<<dim3(HBLK, B), 256, 0, stream>>>(pA, pB, N, phist);
    meganms_kernel<<<B, 1024, 0, stream>>>(pA, pB, boxes, N, phist, out, B);
}